// Round 8
// baseline (501.107 us; speedup 1.0000x reference)
//
#include <hip/hip_runtime.h>
#include <math.h>

#define NPRI 2000
#define DDIM 78
#define NSB 96
#define CH 32                  // priors per chunk
#define NCHK 63                // ceil(2000/32)
#define BPS 16                 // blocks per (sb,branch)
#define F4PC 624               // float4s per chunk (32*78/4)
#define F4PSB 39000            // float4s per sb (2000*78/4)
#define MAXI4 (96 * 39000 - 1) // last valid float4 index within one branch

// ws layout (bytes):
//   0      corrws  f[2][2000]   16,000  (memset 0)
//   16000  regacc  f[16]            64  (memset 0)
//   16064  clsSum  f[2][2000]   16,000  (memset 0, atomic acc)
//   32064  tickets i[200]          800  (memset 0; [0..191]=per-(br,sb), [192]=global)
//   32864  blockTop float2[192][16][4][4]  393,216  (plain stores, fully written)
//   426080 rowsws  i[2][4]          32  (plain store by sb==95 mergers)

__device__ __forceinline__ void lexmin_bfly(float& v, int& i) {
#pragma unroll
    for (int off = 32; off > 0; off >>= 1) {
        float v2 = __shfl_xor(v, off);
        int   i2 = __shfl_xor(i, off);
        if (v2 < v || (v2 == v && i2 < i)) { v = v2; i = i2; }
    }
}

__global__ __launch_bounds__(64) void main_kernel(
    const float* __restrict__ predsA, const float* __restrict__ predsB,
    const float* __restrict__ gt, const float* __restrict__ diff,
    float* __restrict__ corrws, float* __restrict__ regacc,
    float* __restrict__ clsSum, int* __restrict__ tickets,
    float2* __restrict__ blockTop, int* __restrict__ rowsws,
    float* __restrict__ out)
{
    const int bx = blockIdx.x;        // 0..15: handles chunks c = bx + 16k
    const int sb = blockIdx.y;        // 0..95
    const int branch = blockIdx.z;    // 0..1
    const float* preds = branch ? predsB : predsA;
    const int bimg = sb & 31;
    const int lane = threadIdx.x;     // single wave per block

    __shared__ __align__(16) float sbuf[2 * CH * DDIM];   // 19,968 B double buffer
    __shared__ __align__(16) float stg[304];              // [j][l]=t/799 (288) + geo (16)
    __shared__ int seli[2];

    // ---- stage targets (exact same /799 division as reference) ----
    for (int idx = lane; idx < 304; idx += 64) {
        if (idx < 288) {
            int j = idx >> 2, l = idx & 3;
            stg[idx] = gt[((size_t)bimg * 4 + l) * DDIM + 6 + j] / 799.0f;
        } else {
            int g = idx - 288, l = g >> 2, d = g & 3;
            stg[idx] = gt[((size_t)bimg * 4 + l) * DDIM + 2 + d];
        }
    }
    __syncthreads();

    float4 ge[4];
    {
        const float4* gg = (const float4*)(stg + 288);
#pragma unroll
        for (int l = 0; l < 4; ++l) ge[l] = gg[l];
    }

    const float4* pb4 = (const float4*)preds;
    const int base4sb = sb * F4PSB;
    const int pr = lane >> 1, h = lane & 1;
    const int nch = (bx == 15) ? 3 : 4;

    float tv[4][4]; int ti[4][4];
#pragma unroll
    for (int l = 0; l < 4; ++l)
#pragma unroll
        for (int r = 0; r < 4; ++r) { tv[l][r] = INFINITY; ti[l][r] = 0x7fffffff; }

    // ---- software-pipelined chunk loop: no barriers, compiler waitcnts ----
    float4 R[10];
    {
        const int g0 = base4sb + bx * F4PC;
#pragma unroll
        for (int q = 0; q < 10; ++q) {
            int idx = q * 64 + lane;
            if (idx < F4PC) { int gi = g0 + idx; if (gi > MAXI4) gi = MAXI4; R[q] = pb4[gi]; }
        }
        float4* dst = (float4*)sbuf;
#pragma unroll
        for (int q = 0; q < 10; ++q) { int idx = q * 64 + lane; if (idx < F4PC) dst[idx] = R[q]; }
    }

    for (int k = 0; k < nch; ++k) {
        const int c = bx + 16 * k;
        if (k + 1 < nch) {                      // prefetch next chunk into regs
            const int g0 = base4sb + (c + 16) * F4PC;
#pragma unroll
            for (int q = 0; q < 10; ++q) {
                int idx = q * 64 + lane;
                if (idx < F4PC) { int gi = g0 + idx; if (gi > MAXI4) gi = MAXI4; R[q] = pb4[gi]; }
            }
        }
        // compute on current buffer (lane pairs: h = j-half)
        {
            const float* p = sbuf + (k & 1) * (CH * DDIM) + pr * DDIM;
            const int n = c * CH + pr;
            const bool act = (n < NPRI);
            float o0 = 0.f, o1 = 0.f, o2 = 0.f, o3 = 0.f;
            const float4* tq = ((const float4*)stg) + 36 * h;   // uniform -> broadcast
            const float* pj = p + 6 + 36 * h;
#pragma unroll
            for (int jj = 0; jj < 18; ++jj) {
                float2 pv = *(const float2*)(pj + 2 * jj);
                float4 t0 = tq[2 * jj], t1 = tq[2 * jj + 1];
                o0 += fabsf(pv.x - t0.x) + fabsf(pv.y - t1.x);
                o1 += fabsf(pv.x - t0.y) + fabsf(pv.y - t1.y);
                o2 += fabsf(pv.x - t0.z) + fabsf(pv.y - t1.z);
                o3 += fabsf(pv.x - t0.w) + fabsf(pv.y - t1.w);
            }
            o0 += __shfl_xor(o0, 1); o1 += __shfl_xor(o1, 1);
            o2 += __shfl_xor(o2, 1); o3 += __shfl_xor(o3, 1);
            if (act && h == 0) {
                float2 p01 = *(const float2*)(p);
                float2 p23 = *(const float2*)(p + 2);
                float2 p45 = *(const float2*)(p + 4);
                float a = p01.x, b1 = p01.y;
                float m = fmaxf(a, b1);
                float ea = expf(a - m), eb = expf(b1 - m);
                float score = eb / (ea + eb);
                float lse = m + logf(ea + eb);
                float logpt = a - lse;
                float pt = expf(logpt);
                float om = 1.0f - pt;
                atomicAdd(&clsSum[branch * NPRI + n], -(0.1f * om * om * logpt));
                float offs[4] = {o0, o1, o2, o3};
#pragma unroll
                for (int l = 0; l < 4; ++l) {
                    float geo = fabsf(p23.x - ge[l].x) + fabsf(p23.y - ge[l].y)
                              + fabsf(p45.x - ge[l].z) + fabsf(p45.y - ge[l].w);
                    float cst = geo + offs[l] / 72.0f - score;
                    float* V = tv[l]; int* I = ti[l];
                    bool lt3 = cst < V[3] || (cst == V[3] && n < I[3]);
                    if (lt3) {
                        bool lt0 = cst < V[0] || (cst == V[0] && n < I[0]);
                        bool lt1 = cst < V[1] || (cst == V[1] && n < I[1]);
                        bool lt2 = cst < V[2] || (cst == V[2] && n < I[2]);
                        if (lt0) { V[3]=V[2];I[3]=I[2]; V[2]=V[1];I[2]=I[1]; V[1]=V[0];I[1]=I[0]; V[0]=cst;I[0]=n; }
                        else if (lt1) { V[3]=V[2];I[3]=I[2]; V[2]=V[1];I[2]=I[1]; V[1]=cst;I[1]=n; }
                        else if (lt2) { V[3]=V[2];I[3]=I[2]; V[2]=cst;I[2]=n; }
                        else { V[3]=cst; I[3]=n; }
                    }
                }
            }
        }
        if (k + 1 < nch) {                      // write prefetched regs to other buffer
            float4* dst = (float4*)(sbuf + ((k + 1) & 1) * (CH * DDIM));
#pragma unroll
            for (int q = 0; q < 10; ++q) { int idx = q * 64 + lane; if (idx < F4PC) dst[idx] = R[q]; }
        }
    }

    // ---- wave top-4 merge -> blockTop ----
    const int tk = branch * NSB + sb;
    {
        int pc[4] = {0, 0, 0, 0};
#pragma unroll
        for (int l = 0; l < 4; ++l) {
#pragma unroll
            for (int r = 0; r < 4; ++r) {
                float hv = (pc[l]==0)?tv[l][0]:(pc[l]==1)?tv[l][1]:(pc[l]==2)?tv[l][2]:(pc[l]==3)?tv[l][3]:INFINITY;
                int   hi = (pc[l]==0)?ti[l][0]:(pc[l]==1)?ti[l][1]:(pc[l]==2)?ti[l][2]:(pc[l]==3)?ti[l][3]:0x7fffffff;
                float lv = hv; int li = hi;
                lexmin_bfly(lv, li);
                if (lane == 0)
                    blockTop[(size_t)tk * 256 + bx * 16 + l * 4 + r] = make_float2(lv, __int_as_float(li));
                if (li == hi && hi != 0x7fffffff) pc[l]++;
            }
        }
    }
    __threadfence();
    int old;
    if (lane == 0) old = atomicAdd(&tickets[tk], 1);
    old = __shfl(old, 0);
    if (old != BPS - 1) return;

    // ================= merge phase (last block of this (sb,branch)) ========
    __threadfence();
    int topsi[4][4];
    const float2* btk = blockTop + (size_t)tk * 256;
#pragma unroll
    for (int l = 0; l < 4; ++l) {
        float2 e = btk[(lane >> 2) * 16 + l * 4 + (lane & 3)];
        float v = e.x; int id = __float_as_int(e.y);
#pragma unroll
        for (int r = 0; r < 4; ++r) {
            float lv = v; int li = id;
            lexmin_bfly(lv, li);
            topsi[l][r] = li;                   // same in all lanes
            if (li == id) v = INFINITY;         // ids unique (priors partitioned)
        }
    }
    // greedy without replacement (exact jnp.argmin order; <=3 masked rows)
    int rowsv[4];
    rowsv[0] = topsi[0][0];
    { int pick = topsi[1][3];
#pragma unroll
      for (int r = 3; r >= 0; --r) { int c2 = topsi[1][r]; if (c2 != rowsv[0]) pick = c2; }
      rowsv[1] = pick; }
    { int pick = topsi[2][3];
#pragma unroll
      for (int r = 3; r >= 0; --r) { int c2 = topsi[2][r]; if (c2 != rowsv[0] && c2 != rowsv[1]) pick = c2; }
      rowsv[2] = pick; }
    { int pick = topsi[3][3];
#pragma unroll
      for (int r = 3; r >= 0; --r) { int c2 = topsi[3][r]; if (c2 != rowsv[0] && c2 != rowsv[1] && c2 != rowsv[2]) pick = c2; }
      rowsv[3] = pick; }

    if (sb == NSB - 1 && lane < 4) rowsws[branch * 4 + lane] = rowsv[lane];

    const float* gtb = gt + (size_t)bimg * 4 * DDIM;
#pragma unroll
    for (int l = 0; l < 4; ++l) {
        const int row = rowsv[l];
        const float* pm = preds + ((size_t)sb * NPRI + row) * DDIM;
        const float* tg = gtb + l * DDIM;
        float osum = 0.f, usum = 0.f, rterm = 0.f;
        {
            float rp = pm[6 + lane] * 799.0f;
            float rt = tg[6 + lane];
            bool inv = (rt < 0.0f) || (rt >= 800.0f);
            float ov = fminf(rp, rt) - fmaxf(rp, rt) + 30.0f;
            float un = fmaxf(rp, rt) - fminf(rp, rt) + 30.0f;
            if (!inv) { osum += ov; usum += un; }
        }
        if (lane < 8) {
            float rp = pm[70 + lane] * 799.0f;
            float rt = tg[70 + lane];
            bool inv = (rt < 0.0f) || (rt >= 800.0f);
            float ov = fminf(rp, rt) - fmaxf(rp, rt) + 30.0f;
            float un = fmaxf(rp, rt) - fminf(rp, rt) + 30.0f;
            if (!inv) { osum += ov; usum += un; }
        }
        if (lane < 4) {
            const float scv[4] = {71.0f, 799.0f, 180.0f, 71.0f};
            float s = scv[lane];
            float d = pm[2 + lane] * s - tg[2 + lane] * s;
            float ad = fabsf(d);
            rterm = (ad < 1.0f) ? 0.5f * d * d : ad - 0.5f;
        }
#pragma unroll
        for (int off = 32; off > 0; off >>= 1) {
            osum += __shfl_down(osum, off);
            usum += __shfl_down(usum, off);
            rterm += __shfl_down(rterm, off);
        }
        if (lane == 0) {
            float iou = osum / (usum + 1e-9f);
            atomicAdd(&regacc[branch * 8 + l], (rterm / 4.0f) / 4.0f);
            atomicAdd(&regacc[branch * 8 + 4 + l], (1.0f - iou) / 4.0f);
            float a = pm[0], b1 = pm[1];
            float m = fmaxf(a, b1);
            float ea = expf(a - m), eb = expf(b1 - m);
            float lse = m + logf(ea + eb);
            float lp0 = a - lse, lp1 = b1 - lse;
            float pt0 = expf(lp0), pt1 = expf(lp1);
            float om0 = 1.0f - pt0, om1 = 1.0f - pt1;
            float neg = -(0.1f * om0 * om0 * lp0);
            float pos = -(0.9f * om1 * om1 * lp1);
            atomicAdd(&corrws[branch * NPRI + row], pos - neg);
        }
    }
    __threadfence();
    int old2;
    if (lane == 0) old2 = atomicAdd(&tickets[192], 1);
    old2 = __shfl(old2, 0);
    if (old2 != 2 * NSB - 1) return;

    // ================= final phase (last merger; 64 threads) ================
    __threadfence();
    float rA[8], rB[8]; int rwA[4], rwB[4];
#pragma unroll
    for (int q = 0; q < 8; ++q) { rA[q] = regacc[q]; rB[q] = regacc[8 + q]; }
#pragma unroll
    for (int q = 0; q < 4; ++q) { rwA[q] = rowsws[q]; rwB[q] = rowsws[4 + q]; }

    unsigned* keyu = (unsigned*)sbuf;    // reuse tile LDS (8,000 B)
    float acc0 = 0.f, acc1 = 0.f;
#pragma unroll 4
    for (int n = lane; n < NPRI; n += 64) {
        float ia = (clsSum[n] + corrws[n]) * (2.0f / 96.0f);
        float ib = (clsSum[NPRI + n] + corrws[NPRI + n]) * (2.0f / 96.0f);
#pragma unroll
        for (int l = 0; l < 4; ++l) {
            if (rwA[l] == n) ia += (rA[l] / 96.0f) * 0.5f + (rA[4 + l] / 96.0f) * 2.0f;
            if (rwB[l] == n) ib += (rB[l] / 96.0f) * 0.5f + (rB[4 + l] / 96.0f) * 2.0f;
        }
        float dm = (diff[n] + diff[NPRI + n] + diff[2 * NPRI + n]) / 3.0f;
        acc0 += (1.0f - dm) * ia + dm * ib;
        acc1 += 2.0f * dm - 1.0f;
        unsigned s = __float_as_uint(ia - ib);
        keyu[n] = s ^ ((s >> 31) ? 0xFFFFFFFFu : 0x80000000u);
    }
    __syncthreads();

    unsigned* hist = (unsigned*)stg;     // reuse target LDS (1,024 B)
    unsigned kv[2];
    for (int t = 0; t < 2; ++t) {
        int rank = 999 + t;
        unsigned prefix = 0, pmask = 0;
        for (int shift = 24; shift >= 0; shift -= 8) {
#pragma unroll
            for (int q = 0; q < 4; ++q) hist[q * 64 + lane] = 0;
            __syncthreads();
            for (int n = lane; n < NPRI; n += 64) {
                unsigned kk = keyu[n];
                if ((kk & pmask) == prefix) atomicAdd(&hist[(kk >> shift) & 255], 1u);
            }
            __syncthreads();
            int h0 = hist[4 * lane], h1 = hist[4 * lane + 1];
            int h2 = hist[4 * lane + 2], h3 = hist[4 * lane + 3];
            int tot = h0 + h1 + h2 + h3;
            int x = tot;
#pragma unroll
            for (int s2 = 1; s2 < 64; s2 <<= 1) {
                int y = __shfl_up(x, s2);
                if (lane >= s2) x += y;
            }
            int e0 = x - tot, e1 = e0 + h0, e2 = e1 + h1, e3 = e2 + h2;
            if (rank >= e0 && rank < e1)      { seli[0] = 4 * lane;     seli[1] = rank - e0; }
            if (rank >= e1 && rank < e2)      { seli[0] = 4 * lane + 1; seli[1] = rank - e1; }
            if (rank >= e2 && rank < e3)      { seli[0] = 4 * lane + 2; seli[1] = rank - e2; }
            if (rank >= e3 && rank < e3 + h3) { seli[0] = 4 * lane + 3; seli[1] = rank - e3; }
            __syncthreads();
            prefix |= ((unsigned)seli[0]) << shift;
            rank = seli[1];
            pmask |= 0xFFu << shift;
            __syncthreads();
        }
        kv[t] = prefix;
    }
    unsigned u0 = kv[0], u1 = kv[1];
    float m0 = __uint_as_float((u0 & 0x80000000u) ? (u0 ^ 0x80000000u) : ~u0);
    float m1 = __uint_as_float((u1 & 0x80000000u) ? (u1 ^ 0x80000000u) : ~u1);
    float delta = 0.5f * (m0 + m1);

#pragma unroll
    for (int off = 32; off > 0; off >>= 1) {
        acc0 += __shfl_down(acc0, off);
        acc1 += __shfl_down(acc1, off);
    }
    if (lane == 0) out[0] = acc0 + 0.5f * delta * acc1;
}

// ---------------------------------------------------------------------------
extern "C" void kernel_launch(void* const* d_in, const int* in_sizes, int n_in,
                              void* d_out, int out_size, void* d_ws, size_t ws_size,
                              hipStream_t stream)
{
    const float* predsA = (const float*)d_in[0];
    const float* predsB = (const float*)d_in[1];
    const float* gt     = (const float*)d_in[2];
    const float* diff   = (const float*)d_in[3];
    float* out = (float*)d_out;

    float*  corrws   = (float*)d_ws;                          // 4,000 f
    float*  regacc   = corrws + 2 * NPRI;                     //    16 f
    float*  clsSum   = regacc + 16;                           // 4,000 f
    int*    tickets  = (int*)(clsSum + 2 * NPRI);             //   200 i
    float2* blockTop = (float2*)((char*)d_ws + 32864);        // 49,152 float2
    int*    rowsws   = (int*)((char*)d_ws + 32864 + 393216);  //     8 i

    // one memset covers corrws + regacc + clsSum + tickets (32,864 B)
    hipMemsetAsync(d_ws, 0, 32864, stream);

    dim3 g(BPS, NSB, 2);
    main_kernel<<<g, 64, 0, stream>>>(predsA, predsB, gt, diff,
                                      corrws, regacc, clsSum, tickets,
                                      blockTop, rowsws, out);
}

// Round 9
// 366.940 us; speedup vs baseline: 1.3656x; 1.3656x over previous
//
#include <hip/hip_runtime.h>
#include <math.h>

#define NPRI 2000
#define DDIM 78
#define NSB 96
#define CH 64                  // priors per chunk
#define CPB 4                  // chunks per block
#define BPS 8                  // blocks per (sb,branch)
#define F4PC 1248              // float4s per chunk (64*78/4)
#define F4PSB 39000            // float4s per sb (2000*78/4)

// ws layout (bytes):
//   0      corrws  f[2][2000]  16,000  (memset 0, atomic)
//   16000  regacc  f[16]           64  (memset 0, atomic)
//   16064  clsSum  f[2][2000]  16,000  (memset 0, atomic)
//   32064  tickets i[200]         800  (memset 0; [tk] per (br,sb), [192] global)
//   32864  rowsws  i[2][4]         32  (plain store, memset harmless)
//   32896  blockTop float2[192][8][4][4]  196,608  (plain stores, fully written)

__device__ __forceinline__ void lexmin_bfly(float& v, int& i) {
#pragma unroll
    for (int off = 32; off > 0; off >>= 1) {
        float v2 = __shfl_xor(v, off);
        int   i2 = __shfl_xor(i, off);
        if (v2 < v || (v2 == v && i2 < i)) { v = v2; i = i2; }
    }
}

__global__ __launch_bounds__(256) void main_kernel(
    const float* __restrict__ predsA, const float* __restrict__ predsB,
    const float* __restrict__ gt, const float* __restrict__ diff,
    float* __restrict__ corrws, float* __restrict__ regacc,
    float* __restrict__ clsSum, int* __restrict__ tickets,
    int* __restrict__ rowsws, float2* __restrict__ blockTop,
    float* __restrict__ out)
{
    const int bx = blockIdx.x;        // 0..7
    const int sb = blockIdx.y;        // 0..95
    const int branch = blockIdx.z;    // 0..1
    const float* preds = branch ? predsB : predsA;
    const int bimg = sb & 31;
    const int tid = threadIdx.x;
    const int wv = tid >> 6, lane = tid & 63;

    __shared__ __align__(16) float tile[CH * DDIM];   // 19,968 B
    __shared__ __align__(16) float stg[304];          // tg/799 [j][l] (288) + geo (16)
    __shared__ float wtv[4][4][4];
    __shared__ int   wti[4][4][4];
    __shared__ int   flagA, flagB;
    __shared__ unsigned wsum[4];
    __shared__ int selb, selr;
    __shared__ float fred[8];

    // ---- per-block target staging (exact /799 division as reference) ----
    for (int idx = tid; idx < 304; idx += 256) {
        if (idx < 288) {
            int j = idx >> 2, l = idx & 3;
            stg[idx] = gt[((size_t)bimg * 4 + l) * DDIM + 6 + j] / 799.0f;
        } else {
            int g2 = idx - 288, l = g2 >> 2, d = g2 & 3;
            stg[idx] = gt[((size_t)bimg * 4 + l) * DDIM + 2 + d];
        }
    }

    const float4* pb4 = (const float4*)preds;
    const int base4 = sb * F4PSB;

    // per-lane top-4 per l (valid on h==0 lanes)
    float tv[4][4]; int ti[4][4];
#pragma unroll
    for (int l = 0; l < 4; ++l)
#pragma unroll
        for (int r = 0; r < 4; ++r) { tv[l][r] = INFINITY; ti[l][r] = 0x7fffffff; }

    const int i = (wv << 4) + (lane >> 2);   // prior within chunk 0..63
    const int h = lane & 3;                  // j-quarter
    const int j0 = 18 * h;

    // ---- prologue: load chunk c0 into R (static R[5], 256-thread guard) ----
    float4 R[5];
    {
        const int c0 = CPB * bx;
        const int nf4 = min(CH, NPRI - c0 * CH) * DDIM / 4;
        const float4* src = pb4 + base4 + (size_t)c0 * F4PC;
#pragma unroll
        for (int q = 0; q < 5; ++q) {
            int idx = q * 256 + tid;
            if (idx < nf4) R[q] = src[idx];
        }
    }

    for (int k = 0; k < CPB; ++k) {
        const int c = CPB * bx + k;
        const int ntile = min(CH, NPRI - c * CH);
        const int nf4 = ntile * DDIM / 4;
        // write staged regs -> LDS
        {
            float4* dst = (float4*)tile;
#pragma unroll
            for (int q = 0; q < 5; ++q) {
                int idx = q * 256 + tid;
                if (idx < nf4) dst[idx] = R[q];
            }
        }
        __syncthreads();                      // tile (and stg on k=0) ready
        if (k + 1 < CPB) {                    // prefetch next chunk into regs
            const int nf4n = min(CH, NPRI - (c + 1) * CH) * DDIM / 4;
            const float4* src = pb4 + base4 + (size_t)(c + 1) * F4PC;
#pragma unroll
            for (int q = 0; q < 5; ++q) {
                int idx = q * 256 + tid;
                if (idx < nf4n) R[q] = src[idx];
            }
        }
        // compute chunk c
        if (i < ntile) {
            const float* p = &tile[i * DDIM];
            float o0 = 0.f, o1 = 0.f, o2 = 0.f, o3 = 0.f;
            const float4* tg4 = (const float4*)stg;
#pragma unroll
            for (int jj = 0; jj < 9; ++jj) {
                float2 pv = *(const float2*)(p + 6 + j0 + 2 * jj);
                float4 t0 = tg4[j0 + 2 * jj];
                float4 t1 = tg4[j0 + 2 * jj + 1];
                o0 += fabsf(pv.x - t0.x) + fabsf(pv.y - t1.x);
                o1 += fabsf(pv.x - t0.y) + fabsf(pv.y - t1.y);
                o2 += fabsf(pv.x - t0.z) + fabsf(pv.y - t1.z);
                o3 += fabsf(pv.x - t0.w) + fabsf(pv.y - t1.w);
            }
            o0 += __shfl_xor(o0, 1); o1 += __shfl_xor(o1, 1);
            o2 += __shfl_xor(o2, 1); o3 += __shfl_xor(o3, 1);
            o0 += __shfl_xor(o0, 2); o1 += __shfl_xor(o1, 2);
            o2 += __shfl_xor(o2, 2); o3 += __shfl_xor(o3, 2);
            if (h == 0) {
                const int n = c * CH + i;
                float a = p[0], b1 = p[1];
                float m = fmaxf(a, b1);
                float ea = expf(a - m), eb = expf(b1 - m);
                float score = eb / (ea + eb);
                float lse = m + logf(ea + eb);
                float logpt = a - lse;
                float pt = expf(logpt);
                float om = 1.0f - pt;
                atomicAdd(&clsSum[branch * NPRI + n], -(0.1f * om * om * logpt));
                const float* ge = stg + 288;
                float offs[4] = {o0, o1, o2, o3};
#pragma unroll
                for (int l = 0; l < 4; ++l) {
                    float geo = fabsf(p[2] - ge[l * 4 + 0]) + fabsf(p[3] - ge[l * 4 + 1])
                              + fabsf(p[4] - ge[l * 4 + 2]) + fabsf(p[5] - ge[l * 4 + 3]);
                    float cst = geo + offs[l] / 72.0f - score;
                    float* V = tv[l]; int* I = ti[l];
                    bool lt3 = cst < V[3] || (cst == V[3] && n < I[3]);
                    if (lt3) {
                        bool lt0 = cst < V[0] || (cst == V[0] && n < I[0]);
                        bool lt1 = cst < V[1] || (cst == V[1] && n < I[1]);
                        bool lt2 = cst < V[2] || (cst == V[2] && n < I[2]);
                        if (lt0) { V[3]=V[2];I[3]=I[2]; V[2]=V[1];I[2]=I[1]; V[1]=V[0];I[1]=I[0]; V[0]=cst;I[0]=n; }
                        else if (lt1) { V[3]=V[2];I[3]=I[2]; V[2]=V[1];I[2]=I[1]; V[1]=cst;I[1]=n; }
                        else if (lt2) { V[3]=V[2];I[3]=I[2]; V[2]=cst;I[2]=n; }
                        else { V[3]=cst; I[3]=n; }
                    }
                }
            }
        }
        __syncthreads();                      // all reads done before next write
    }

    // ---- wave top-4 merge (once per block) ----
    {
        int pc[4] = {0, 0, 0, 0};
#pragma unroll
        for (int l = 0; l < 4; ++l) {
#pragma unroll
            for (int r = 0; r < 4; ++r) {
                float hv = (pc[l]==0)?tv[l][0]:(pc[l]==1)?tv[l][1]:(pc[l]==2)?tv[l][2]:(pc[l]==3)?tv[l][3]:INFINITY;
                int   hi = (pc[l]==0)?ti[l][0]:(pc[l]==1)?ti[l][1]:(pc[l]==2)?ti[l][2]:(pc[l]==3)?ti[l][3]:0x7fffffff;
                float lv = hv; int li = hi;
                lexmin_bfly(lv, li);
                if (lane == 0) { wtv[wv][l][r] = lv; wti[wv][l][r] = li; }
                if (li == hi && hi != 0x7fffffff) pc[l]++;
            }
        }
    }
    __syncthreads();

    const int tk = branch * NSB + sb;
    // wave 0 merges 4 waves' top-4 -> block top-4 -> blockTop
    if (wv == 0) {
#pragma unroll
        for (int l = 0; l < 4; ++l) {
            float v = INFINITY; int id = 0x7fffffff;
            if (lane < 16) { v = wtv[lane >> 2][l][lane & 3]; id = wti[lane >> 2][l][lane & 3]; }
#pragma unroll
            for (int r = 0; r < 4; ++r) {
                float lv = v; int li = id;
                lexmin_bfly(lv, li);
                if (lane == 0)
                    blockTop[((size_t)(tk * BPS + bx) * 4 + l) * 4 + r] = make_float2(lv, __int_as_float(li));
                if (li == id && id != 0x7fffffff) v = INFINITY;
            }
        }
    }
    // ---- per-(sb,branch) ticket ----
    if (tid == 0) {
        __threadfence();
        int old = atomicAdd(&tickets[tk], 1);
        flagA = (old == BPS - 1) ? 1 : 0;
    }
    __syncthreads();
    if (!flagA) return;
    __threadfence();

    // ================= merge phase (wave 0 of the last block) ===============
    if (wv == 0) {
        int topsi[4][4];
#pragma unroll
        for (int l = 0; l < 4; ++l) {
            float v = INFINITY; int id = 0x7fffffff;
            if (lane < 32) {
                float2 e = blockTop[((size_t)(tk * BPS + (lane >> 2)) * 4 + l) * 4 + (lane & 3)];
                v = e.x; id = __float_as_int(e.y);
            }
#pragma unroll
            for (int r = 0; r < 4; ++r) {
                float lv = v; int li = id;
                lexmin_bfly(lv, li);
                topsi[l][r] = li;
                if (li == id && id != 0x7fffffff) v = INFINITY;
            }
        }
        int rowsv[4];
        rowsv[0] = topsi[0][0];
        { int pick = topsi[1][3];
#pragma unroll
          for (int r = 3; r >= 0; --r) { int c2 = topsi[1][r]; if (c2 != rowsv[0]) pick = c2; }
          rowsv[1] = pick; }
        { int pick = topsi[2][3];
#pragma unroll
          for (int r = 3; r >= 0; --r) { int c2 = topsi[2][r]; if (c2 != rowsv[0] && c2 != rowsv[1]) pick = c2; }
          rowsv[2] = pick; }
        { int pick = topsi[3][3];
#pragma unroll
          for (int r = 3; r >= 0; --r) { int c2 = topsi[3][r]; if (c2 != rowsv[0] && c2 != rowsv[1] && c2 != rowsv[2]) pick = c2; }
          rowsv[3] = pick; }

        if (sb == NSB - 1 && lane < 4) rowsws[branch * 4 + lane] = rowsv[lane];

        const float* gtb = gt + (size_t)bimg * 4 * DDIM;
#pragma unroll
        for (int l = 0; l < 4; ++l) {
            const int row = rowsv[l];
            const float* pm = preds + ((size_t)sb * NPRI + row) * DDIM;
            const float* tg = gtb + l * DDIM;
            float osum = 0.f, usum = 0.f, rterm = 0.f;
            {
                float rp = pm[6 + lane] * 799.0f;
                float rt = tg[6 + lane];
                bool inv = (rt < 0.0f) || (rt >= 800.0f);
                float ov = fminf(rp, rt) - fmaxf(rp, rt) + 30.0f;
                float un = fmaxf(rp, rt) - fminf(rp, rt) + 30.0f;
                if (!inv) { osum += ov; usum += un; }
            }
            if (lane < 8) {
                float rp = pm[70 + lane] * 799.0f;
                float rt = tg[70 + lane];
                bool inv = (rt < 0.0f) || (rt >= 800.0f);
                float ov = fminf(rp, rt) - fmaxf(rp, rt) + 30.0f;
                float un = fmaxf(rp, rt) - fminf(rp, rt) + 30.0f;
                if (!inv) { osum += ov; usum += un; }
            }
            if (lane < 4) {
                const float scv[4] = {71.0f, 799.0f, 180.0f, 71.0f};
                float s = scv[lane];
                float d = pm[2 + lane] * s - tg[2 + lane] * s;
                float ad = fabsf(d);
                rterm = (ad < 1.0f) ? 0.5f * d * d : ad - 0.5f;
            }
#pragma unroll
            for (int off = 32; off > 0; off >>= 1) {
                osum += __shfl_down(osum, off);
                usum += __shfl_down(usum, off);
                rterm += __shfl_down(rterm, off);
            }
            if (lane == 0) {
                float iou = osum / (usum + 1e-9f);
                atomicAdd(&regacc[branch * 8 + l], (rterm / 4.0f) / 4.0f);
                atomicAdd(&regacc[branch * 8 + 4 + l], (1.0f - iou) / 4.0f);
                float a = pm[0], b1 = pm[1];
                float m = fmaxf(a, b1);
                float ea = expf(a - m), eb = expf(b1 - m);
                float lse = m + logf(ea + eb);
                float lp0 = a - lse, lp1 = b1 - lse;
                float pt0 = expf(lp0), pt1 = expf(lp1);
                float om0 = 1.0f - pt0, om1 = 1.0f - pt1;
                float neg = -(0.1f * om0 * om0 * lp0);
                float pos = -(0.9f * om1 * om1 * lp1);
                atomicAdd(&corrws[branch * NPRI + row], pos - neg);
            }
        }
    }
    __syncthreads();
    // ---- global ticket ----
    if (tid == 0) {
        __threadfence();
        int old = atomicAdd(&tickets[192], 1);
        flagB = (old == 2 * NSB - 1) ? 1 : 0;
    }
    __syncthreads();
    if (!flagB) return;
    __threadfence();

    // ================= final phase (one block, 256 threads) =================
    float rA[8], rB[8]; int rwA[4], rwB[4];
#pragma unroll
    for (int q = 0; q < 8; ++q) { rA[q] = regacc[q]; rB[q] = regacc[8 + q]; }
#pragma unroll
    for (int q = 0; q < 4; ++q) { rwA[q] = rowsws[q]; rwB[q] = rowsws[4 + q]; }

    unsigned* keyu = (unsigned*)tile;     // 8,000 B reuse
    unsigned* hist = (unsigned*)stg;      // 1,024 B reuse
    float acc0 = 0.f, acc1 = 0.f;
    for (int n = tid; n < NPRI; n += 256) {
        float ia = (clsSum[n] + corrws[n]) * (2.0f / 96.0f);
        float ib = (clsSum[NPRI + n] + corrws[NPRI + n]) * (2.0f / 96.0f);
#pragma unroll
        for (int l = 0; l < 4; ++l) {
            if (rwA[l] == n) ia += (rA[l] / 96.0f) * 0.5f + (rA[4 + l] / 96.0f) * 2.0f;
            if (rwB[l] == n) ib += (rB[l] / 96.0f) * 0.5f + (rB[4 + l] / 96.0f) * 2.0f;
        }
        float dm = (diff[n] + diff[NPRI + n] + diff[2 * NPRI + n]) / 3.0f;
        acc0 += (1.0f - dm) * ia + dm * ib;
        acc1 += 2.0f * dm - 1.0f;
        unsigned s = __float_as_uint(ia - ib);
        keyu[n] = s ^ ((s >> 31) ? 0xFFFFFFFFu : 0x80000000u);
    }
    __syncthreads();

    unsigned kv[2];
    for (int t = 0; t < 2; ++t) {
        int rank = 999 + t;
        unsigned prefix = 0, pmask = 0;
        for (int shift = 24; shift >= 0; shift -= 8) {
            hist[tid] = 0;
            __syncthreads();
            for (int n = tid; n < NPRI; n += 256) {
                unsigned kk = keyu[n];
                if ((kk & pmask) == prefix) atomicAdd(&hist[(kk >> shift) & 255], 1u);
            }
            __syncthreads();
            unsigned cnt = hist[tid];
            unsigned x = cnt;
#pragma unroll
            for (int s2 = 1; s2 < 64; s2 <<= 1) {
                unsigned y = __shfl_up(x, s2);
                if (lane >= s2) x += y;
            }
            if (lane == 63) wsum[wv] = x;
            __syncthreads();
            unsigned off = 0;
            for (int w = 0; w < wv; ++w) off += wsum[w];
            unsigned incl = x + off, excl = incl - cnt;
            if ((int)excl <= rank && rank < (int)incl) { selb = tid; selr = rank - (int)excl; }
            __syncthreads();
            prefix |= ((unsigned)selb << shift);
            rank = selr;
            pmask |= (0xFFu << shift);
            __syncthreads();
        }
        kv[t] = prefix;
    }
    unsigned u0 = kv[0], u1 = kv[1];
    float m0 = __uint_as_float((u0 & 0x80000000u) ? (u0 ^ 0x80000000u) : ~u0);
    float m1 = __uint_as_float((u1 & 0x80000000u) ? (u1 ^ 0x80000000u) : ~u1);
    float delta = 0.5f * (m0 + m1);

#pragma unroll
    for (int off = 32; off > 0; off >>= 1) {
        acc0 += __shfl_down(acc0, off);
        acc1 += __shfl_down(acc1, off);
    }
    if (lane == 0) { fred[wv] = acc0; fred[4 + wv] = acc1; }
    __syncthreads();
    if (tid == 0) {
        float a0 = fred[0] + fred[1] + fred[2] + fred[3];
        float a1 = fred[4] + fred[5] + fred[6] + fred[7];
        out[0] = a0 + 0.5f * delta * a1;
    }
}

// ---------------------------------------------------------------------------
extern "C" void kernel_launch(void* const* d_in, const int* in_sizes, int n_in,
                              void* d_out, int out_size, void* d_ws, size_t ws_size,
                              hipStream_t stream)
{
    const float* predsA = (const float*)d_in[0];
    const float* predsB = (const float*)d_in[1];
    const float* gt     = (const float*)d_in[2];
    const float* diff   = (const float*)d_in[3];
    float* out = (float*)d_out;

    float*  corrws   = (float*)d_ws;                      // 4,000 f
    float*  regacc   = corrws + 2 * NPRI;                 //    16 f
    float*  clsSum   = regacc + 16;                       // 4,000 f
    int*    tickets  = (int*)(clsSum + 2 * NPRI);         //   200 i
    int*    rowsws   = tickets + 200;                     //     8 i
    float2* blockTop = (float2*)((char*)d_ws + 32896);    // 24,576 float2

    // zero corrws + regacc + clsSum + tickets + rowsws in one node
    hipMemsetAsync(d_ws, 0, 32896, stream);

    dim3 g(BPS, NSB, 2);
    main_kernel<<<g, 256, 0, stream>>>(predsA, predsB, gt, diff,
                                       corrws, regacc, clsSum, tickets,
                                       rowsws, blockTop, out);
}